// Round 8
// baseline (166.185 us; speedup 1.0000x reference)
//
#include <hip/hip_runtime.h>
#include <hip/hip_bf16.h>
#include <stdint.h>

// B,C,H,W = 2,64,96,96. Inputs fp32, output fp32.
// *** ROUND-8 ATTRIBUTION PROBE ***: proj3 is launched 4x (idempotent: pure
// function of inputs, disjoint stores). attn13 + combine verbatim controls.
// P_proj = (T8 - A8 - (T7 - A7)) / 3 resolves where the persistent ~80µs of
// non-attn time lives (proj3 vs combine+overhead) -- neither has ever been
// visible in the top-5 window.
// proj3 (round-0 verbatim): QKV 1x1 convs -> bf16 q(*log2e), k, V key-PERMUTED
//        channel-major.
// attn13 (round-7 verbatim): 3-buffer counted-vmcnt LDS pipeline, ones-MFMA
//        lsum, XOR-swizzled V, XCD remap blockIdx = qt*8 + (g*BB+b).
// combine: sum G key-split partials, normalize, + gamma*attn + x.
#define BB 2
#define CC 64
#define PP 9216
#define QTILES 144               // PP/64
#define LOG2E 1.4426950408889634f
// big-constant Schraudolph: low16(E*128 + 16248.665 + 1.5*2^23) = bf16 bits of 2^E
#define SCH_BC 12599160.0f

typedef unsigned short ushort;
typedef __attribute__((ext_vector_type(8))) short short8;
typedef __attribute__((ext_vector_type(4))) float floatx4;
typedef __attribute__((ext_vector_type(4))) int intx4;

__device__ __forceinline__ ushort f2bf(float f) {
    unsigned int u = __float_as_uint(f);
    u = (u + 0x7fffu + ((u >> 16) & 1u)) >> 16;   // RNE
    return (ushort)u;
}

// 2^e0, 2^e1 as packed bf16 pair: add-big-constant Schraudolph (no v_cvt),
// then one v_perm_b32 splices the two low16 halves.
__device__ __forceinline__ unsigned int exp2_pk_bf16(float e0, float e1) {
    const float t0 = fmaf(e0, 128.f, SCH_BC);
    const float t1 = fmaf(e1, 128.f, SCH_BC);
    // result bytes: [t0.b0, t0.b1, t1.b0, t1.b1]
    return __builtin_amdgcn_perm(__float_as_uint(t1), __float_as_uint(t0),
                                 0x05040100u);
}

__device__ __forceinline__ void gload16_lds(const void* g, void* lds_base) {
    __builtin_amdgcn_global_load_lds(
        (const __attribute__((address_space(1))) unsigned int*)g,
        (__attribute__((address_space(3))) unsigned int*)lds_base, 16, 0, 0);
}

// ---------------------------------------------------------------------------
// Kernel 1: QKV projection (round-0 proj3, verbatim). 576 blocks x 256
// (4 waves; wave = 64 px x 10 rows; 2 blocks per 64-px tile, each covering
// 40 of the 80 output rows). Rows 0-7: q (*LOG2E), 8-15: k, 16-79: v.
// V keys permuted within 32-groups: slot = ((k>>2)&3)*8 + ((k>>4)&1)*4 + (k&3)
// so PV's B-operand slot k'=quad*8+j matches QK's D[key][q] output rows.
// ---------------------------------------------------------------------------
__global__ __launch_bounds__(256)
void proj3(const float* __restrict__ x,
           const float* __restrict__ Wq, const float* __restrict__ bq,
           const float* __restrict__ Wk, const float* __restrict__ bk,
           const float* __restrict__ Wv, const float* __restrict__ bv,
           ushort* __restrict__ qbuf, ushort* __restrict__ kbuf,
           ushort* __restrict__ vfw)
{
    const int tid = threadIdx.x;
    const int px  = tid & 63;
    const int og  = __builtin_amdgcn_readfirstlane(tid >> 6);  // 0..3, wave-uniform
    const int blk = blockIdx.x;
    const int b     = blk / (2 * QTILES);
    const int rem   = blk % (2 * QTILES);
    const int ptile = rem >> 1;
    const int rhalf = rem & 1;
    const int p     = ptile * 64 + px;
    const int r0    = rhalf * 40 + og * 10;      // first of this thread's 10 rows

    const float* wr[10];
#pragma unroll
    for (int r = 0; r < 10; ++r) {
        const int row = r0 + r;
        wr[r] = (row < 8) ? (Wq + row * 64)
              : (row < 16) ? (Wk + (row - 8) * 64)
              : (Wv + (row - 16) * 64);
    }

    float xv[64];
#pragma unroll
    for (int c = 0; c < 64; ++c)
        xv[c] = x[((size_t)b * 64 + c) * PP + p];

    float acc[10];
#pragma unroll
    for (int r = 0; r < 10; ++r) acc[r] = 0.f;
#pragma unroll
    for (int c = 0; c < 64; ++c) {
#pragma unroll
        for (int r = 0; r < 10; ++r)
            acc[r] = fmaf(wr[r][c], xv[c], acc[r]);
    }

#pragma unroll
    for (int r = 0; r < 10; ++r) {
        const int row = r0 + r;
        if (row < 8) {
            const float v = (acc[r] + bq[row]) * LOG2E;
            qbuf[((size_t)b * PP + p) * 8 + row] = f2bf(v);
        } else if (row < 16) {
            const float v = acc[r] + bk[row - 8];
            kbuf[((size_t)b * PP + p) * 8 + (row - 8)] = f2bf(v);
        } else {
            const int co = row - 16;
            const float v = acc[r] + bv[co];
            const int pl = p & 31;     // slot permutation within 32-group
            const int ps = (p & ~31) | ((((pl >> 2) & 3) << 3) | (((pl >> 4) & 1) << 2) | (pl & 3));
            vfw[((size_t)b * 64 + co) * PP + ps] = f2bf(v);
        }
    }
}

// ---------------------------------------------------------------------------
// Kernel 2: LDS-staged MFMA flash attention, 3-buffer counted-vmcnt pipeline,
// XCD-partitioned (round-7 verbatim). Grid = QTILES*8 blocks of 128;
// blockIdx = qt*8 + gb, gb = g*BB+b (round-robin XCD assignment -> one (g,b)
// key-slice per XCD; FETCH 10.5MB -> 1.9MB measured).
// Per 9216B buffer: V 8KB (rows XOR-swizzled) + K 1KB; 3 buffers; epilogue
// smerge (16KB) overlays bufs 0-1 after the final vmcnt(0)+barrier.
// Each wave issues EXACTLY 5 gload_lds per stage; vmcnt(5) at iter top
// proves stage(t) landed; barrier fences buf reuse. Final tile peeled.
// QK: E = mfma(A=K, B=Q) -> D[key][q]; P = Schraudolph bf16 bits = PV
// B-operand (V key-permuted); lsum = ones-row MFMA.
// ---------------------------------------------------------------------------
__global__ __launch_bounds__(128, 3)
void attn13(const ushort* __restrict__ qbuf, const ushort* __restrict__ kbuf,
            const ushort* __restrict__ vfw,
            ushort* __restrict__ accp, float* __restrict__ lsump,
            int keysPerG, int numTiles)
{
    // 0..27648: 3x (V 8KB + K 1KB) | 27648..27904: slsum
    // smerge (16KB f32) overlays 0..16384 after the loop.
    __shared__ __align__(16) char sbuf[27904];
    float* smerge = (float*)sbuf;
    float* slsum  = (float*)(sbuf + 27648);

    const int tid  = threadIdx.x;
    const int lane = tid & 63;
    const int kh   = tid >> 6;        // wave id = key half (0/1)
    const int col  = lane & 15;
    const int quad = lane >> 4;

    // XCD-aware decode: consecutive blockIdx round-robin across the 8 XCDs,
    // so gb = blockIdx & 7 pins each (g,b) key-slice to one XCD's L2.
    const int qt = blockIdx.x >> 3;   // 0..143
    const int gb = blockIdx.x & 7;    // 0..7 = g*BB+b
    const int b  = gb % BB;
    const int g  = gb / BB;
    const int q0 = qt * 64;

    const short8 zf = {0, 0, 0, 0, 0, 0, 0, 0};
    const short vone = (short)0x3F80;                 // bf16 1.0
    const short8 vones = {vone, vone, vone, vone, vone, vone, vone, vone};

    // Q fragments (B-operand: B[k=d=quad*8+j][n=q=col]); only quad 0 real.
    short8 qfragB[4];
#pragma unroll
    for (int qh = 0; qh < 4; ++qh)
        qfragB[qh] = (quad == 0)
            ? *(const short8*)(qbuf + ((size_t)b * PP + q0 + qh * 16 + col) * 8)
            : zf;

    floatx4 acc[4][4];
#pragma unroll
    for (int qh = 0; qh < 4; ++qh)
#pragma unroll
        for (int cb = 0; cb < 4; ++cb) acc[qh][cb] = (floatx4){0.f, 0.f, 0.f, 0.f};
    floatx4 accLh[4];
#pragma unroll
    for (int qh = 0; qh < 4; ++qh) accLh[qh] = (floatx4){0.f, 0.f, 0.f, 0.f};

    const ushort* kB = kbuf + (size_t)b * PP * 8;
    const ushort* vB = vfw + (size_t)b * 64 * PP;
    const int kwbase = g * keysPerG;

    // per-lane staging geometry: lane covers (row-in-8-group vr, chunk_pos lane&7)
    const int vr = lane >> 3;                 // 0..7
    const int vc = (lane & 7) ^ vr;           // swizzled logical chunk for this slot

    auto stage = [&](int t) {
        const int kw = kwbase + t * 64;
        char* Vb = sbuf + 9216 * (t % 3);
        // K: 64 rows x 16B; BOTH waves issue it (same bytes) so each wave's
        // per-stage gload count is exactly 5 (vmcnt accounting).
        gload16_lds(kB + (size_t)(kw + lane) * 8, Vb + 8192);
        const int j0 = kh * 4;
#pragma unroll
        for (int j = 0; j < 4; ++j) {
            const int r = (j0 + j) * 8 + vr;                       // ch row 0..63
            gload16_lds(vB + (size_t)r * PP + kw + vc * 8, Vb + (j0 + j) * 1024);
        }
    };

    auto compute = [&](int t) {
        const char* Vb = sbuf + 9216 * (t % 3);
        const ushort* Kl = (const ushort*)(Vb + 8192);
        // K A-operand rows = keys; all quads read quad0's 16B (broadcast, slots
        // >=8 multiply Q zeros).
        const short8 kf0 = *(const short8*)(Kl + (kh * 32 + col) * 8);
        const short8 kf1 = *(const short8*)(Kl + (kh * 32 + 16 + col) * 8);
        short8 vf[4];
        const int ce = (kh * 4 + quad) ^ (col & 7);   // swizzled chunk to read
#pragma unroll
        for (int cb = 0; cb < 4; ++cb)
            vf[cb] = *(const short8*)(Vb + ((cb * 16 + col) * 8 + ce) * 16);

#pragma unroll
        for (int qh = 0; qh < 4; ++qh) {
            const floatx4 E0 = __builtin_amdgcn_mfma_f32_16x16x32_bf16(
                kf0, qfragB[qh], (floatx4){0.f, 0.f, 0.f, 0.f}, 0, 0, 0);
            const floatx4 E1 = __builtin_amdgcn_mfma_f32_16x16x32_bf16(
                kf1, qfragB[qh], (floatx4){0.f, 0.f, 0.f, 0.f}, 0, 0, 0);

            // Schraudolph bf16 P, packed pairs (slots quad*8 + 0..7)
            intx4 pi;
            pi.x = (int)exp2_pk_bf16(E0[0], E0[1]);
            pi.y = (int)exp2_pk_bf16(E0[2], E0[3]);
            pi.z = (int)exp2_pk_bf16(E1[0], E1[1]);
            pi.w = (int)exp2_pk_bf16(E1[2], E1[3]);
            const short8 pf = __builtin_bit_cast(short8, pi);

            // lsum on the matrix pipe: D[r][c] = sum_k P[k][c] for every r.
            accLh[qh] = __builtin_amdgcn_mfma_f32_16x16x32_bf16(vones, pf, accLh[qh], 0, 0, 0);
#pragma unroll
            for (int cb = 0; cb < 4; ++cb)
                acc[qh][cb] = __builtin_amdgcn_mfma_f32_16x16x32_bf16(
                    vf[cb], pf, acc[qh][cb], 0, 0, 0);
        }
    };

    // ---- 3-buffer counted-vmcnt main loop ----
    stage(0);
    stage(1);                                   // outstanding: 10 per wave
    for (int t = 0; t < numTiles - 1; ++t) {
        asm volatile("s_waitcnt vmcnt(5)" ::: "memory");   // stage(t) landed
        __builtin_amdgcn_s_barrier();                      // both waves agree
        __builtin_amdgcn_sched_barrier(0);
        if (t + 2 < numTiles) stage(t + 2);                // buf[(t+2)%3]
        compute(t);
    }
    asm volatile("s_waitcnt vmcnt(0)" ::: "memory");       // last stage landed
    __builtin_amdgcn_s_barrier();
    __builtin_amdgcn_sched_barrier(0);
    compute(numTiles - 1);
    __syncthreads();            // all buf reads done before smerge overlay

    // ---- merge the two waves' key-halves via LDS; wave 0 stores ----
    if (kh == 1) {
#pragma unroll
        for (int qh = 0; qh < 4; ++qh)
#pragma unroll
            for (int cb = 0; cb < 4; ++cb)
#pragma unroll
                for (int r = 0; r < 4; ++r)
                    smerge[(cb * 16 + quad * 4 + r) * 64 + qh * 16 + col] = acc[qh][cb][r];
        if (quad == 0)
#pragma unroll
            for (int qh = 0; qh < 4; ++qh)
                slsum[qh * 16 + col] = accLh[qh][0];
    }
    __syncthreads();
    if (kh == 0) {
        ushort* ab = accp + ((size_t)g * BB + b) * CC * PP;
#pragma unroll
        for (int qh = 0; qh < 4; ++qh)
#pragma unroll
            for (int cb = 0; cb < 4; ++cb)
#pragma unroll
                for (int r = 0; r < 4; ++r) {
                    const int c = cb * 16 + quad * 4 + r;
                    const float v = acc[qh][cb][r] + smerge[c * 64 + qh * 16 + col];
                    ab[(size_t)c * PP + q0 + qh * 16 + col] = f2bf(v);
                }
        if (quad == 0) {
            float* lb = lsump + ((size_t)g * BB + b) * PP + q0;
#pragma unroll
            for (int qh = 0; qh < 4; ++qh)
                lb[qh * 16 + col] = accLh[qh][0] + slsum[qh * 16 + col];
        }
    }
}

// ---------------------------------------------------------------------------
// Kernel 3: combine G partials, normalize, + gamma*attn + x. 576 x 256,
// 8 consecutive pixels per thread (layouts already [b][c][p]-major).
// ---------------------------------------------------------------------------
__global__ __launch_bounds__(256)
void combine(const ushort* __restrict__ accp, const float* __restrict__ lsump,
             const float* __restrict__ x, const float* __restrict__ gamma,
             float* __restrict__ out, int G)
{
    const size_t i8 = ((size_t)blockIdx.x * 256 + threadIdx.x) * 8;
    const int b = (int)(i8 / ((size_t)CC * PP));
    const int p = (int)(i8 % PP);
    const float gm = gamma[0];

    float asum[8] = {}, lst[8] = {};
    for (int g = 0; g < G; ++g) {
        const uint4 av = *(const uint4*)(accp + (size_t)g * (BB * CC * PP) + i8);
        const unsigned int u[4] = {av.x, av.y, av.z, av.w};
#pragma unroll
        for (int k = 0; k < 4; ++k) {
            asum[2 * k]     += __uint_as_float(u[k] << 16);
            asum[2 * k + 1] += __uint_as_float(u[k] & 0xffff0000u);
        }
        const float* lp = lsump + ((size_t)g * BB + b) * PP + p;
        const float4 l0 = *(const float4*)lp;
        const float4 l1 = *(const float4*)(lp + 4);
        lst[0] += l0.x; lst[1] += l0.y; lst[2] += l0.z; lst[3] += l0.w;
        lst[4] += l1.x; lst[5] += l1.y; lst[6] += l1.z; lst[7] += l1.w;
    }

    const float4 x0 = *(const float4*)(x + i8);
    const float4 x1 = *(const float4*)(x + i8 + 4);
    float o[8] = {x0.x, x0.y, x0.z, x0.w, x1.x, x1.y, x1.z, x1.w};
#pragma unroll
    for (int j = 0; j < 8; ++j)
        o[j] = fmaf(asum[j], gm / fmaxf(lst[j], 1e-30f), o[j]);
    *(float4*)(out + i8)     = make_float4(o[0], o[1], o[2], o[3]);
    *(float4*)(out + i8 + 4) = make_float4(o[4], o[5], o[6], o[7]);
}

// ---------------------------------------------------------------------------
extern "C" void kernel_launch(void* const* d_in, const int* in_sizes, int n_in,
                              void* d_out, int out_size, void* d_ws, size_t ws_size,
                              hipStream_t stream)
{
    const float* x     = (const float*)d_in[0];
    const float* Wq    = (const float*)d_in[1];
    const float* bq    = (const float*)d_in[2];
    const float* Wk    = (const float*)d_in[3];
    const float* bk    = (const float*)d_in[4];
    const float* Wv    = (const float*)d_in[5];
    const float* bv    = (const float*)d_in[6];
    const float* gamma = (const float*)d_in[7];
    float* out = (float*)d_out;

    // ws: qbuf | kbuf | vfw (bf16) | accp (bf16, G slots) | lsump (f32)
    const size_t nQK  = (size_t)BB * PP * 8;        // elems
    const size_t nV   = (size_t)BB * CC * PP;
    // G=4 fixed: g*BB+b spans exactly 8 values = 8 XCDs (attn13 swizzle).
    const int G = 4;
    const int keysPerG = PP / G;
    const int numTiles = keysPerG / 64;             // 36

    ushort* qbuf = (ushort*)d_ws;
    ushort* kbuf = qbuf + nQK;
    ushort* vfw  = kbuf + nQK;
    ushort* accp = vfw + nV;
    float* lsump = (float*)(accp + (size_t)G * nV);
    (void)ws_size;

    // *** PROBE: proj3 x4 (idempotent). P = (T8 - A8 - (T7 - A7)) / 3. ***
    for (int rep = 0; rep < 4; ++rep)
        proj3<<<dim3(BB * 2 * QTILES), dim3(256), 0, stream>>>(
            x, Wq, bq, Wk, bk, Wv, bv, qbuf, kbuf, vfw);
    attn13<<<dim3(QTILES * 8), dim3(128), 0, stream>>>(
        qbuf, kbuf, vfw, accp, lsump, keysPerG, numTiles);
    combine<<<dim3(576), dim3(256), 0, stream>>>(
        accp, lsump, x, gamma, out, G);
}

// Round 9
// 118.176 us; speedup vs baseline: 1.4062x; 1.4062x over previous
//
#include <hip/hip_runtime.h>
#include <hip/hip_bf16.h>
#include <stdint.h>

// B,C,H,W = 2,64,96,96. Inputs fp32, output fp32.
// Budget (round-8 probe): attn 42.5µs, proj 12.5µs, combine ~5-10µs,
// fixed per-iteration harness overhead ~65µs (invariant to launch count).
// proj6: QKV 1x1 convs, latency-hiding rework of proj3 (12.5µs was 4x off
//        roofline): (a) c-loop chunked 16-at-a-time (#pragma unroll 1) so
//        x loads interleave with FMAs instead of a 64-load burst behind
//        ~110 live VGPRs; (b) 4 row-blocks per 64-px tile (20 rows each)
//        -> grid 1152, 4.5 waves/SIMD (was 2.25). Same outputs: bf16
//        q(*log2e), k, V key-PERMUTED channel-major.
// attn13 (round-7 verbatim): 3-buffer counted-vmcnt LDS pipeline, ones-MFMA
//        lsum, XOR-swizzled V, XCD remap blockIdx = qt*8 + (g*BB+b)
//        (FETCH 10.5MB -> 1.9MB measured).
// combine: sum G key-split partials, normalize, + gamma*attn + x.
#define BB 2
#define CC 64
#define PP 9216
#define QTILES 144               // PP/64
#define LOG2E 1.4426950408889634f
// big-constant Schraudolph: low16(E*128 + 16248.665 + 1.5*2^23) = bf16 bits of 2^E
#define SCH_BC 12599160.0f

typedef unsigned short ushort;
typedef __attribute__((ext_vector_type(8))) short short8;
typedef __attribute__((ext_vector_type(4))) float floatx4;
typedef __attribute__((ext_vector_type(4))) int intx4;

__device__ __forceinline__ ushort f2bf(float f) {
    unsigned int u = __float_as_uint(f);
    u = (u + 0x7fffu + ((u >> 16) & 1u)) >> 16;   // RNE
    return (ushort)u;
}

// 2^e0, 2^e1 as packed bf16 pair: add-big-constant Schraudolph (no v_cvt),
// then one v_perm_b32 splices the two low16 halves.
__device__ __forceinline__ unsigned int exp2_pk_bf16(float e0, float e1) {
    const float t0 = fmaf(e0, 128.f, SCH_BC);
    const float t1 = fmaf(e1, 128.f, SCH_BC);
    // result bytes: [t0.b0, t0.b1, t1.b0, t1.b1]
    return __builtin_amdgcn_perm(__float_as_uint(t1), __float_as_uint(t0),
                                 0x05040100u);
}

__device__ __forceinline__ void gload16_lds(const void* g, void* lds_base) {
    __builtin_amdgcn_global_load_lds(
        (const __attribute__((address_space(1))) unsigned int*)g,
        (__attribute__((address_space(3))) unsigned int*)lds_base, 16, 0, 0);
}

// ---------------------------------------------------------------------------
// Kernel 1: QKV projection, latency-hiding layout. 1152 blocks x 256
// (4 waves; 4 blocks per 64-px tile, each covering 20 of the 80 output rows;
// wave = 64 px x 5 rows). Rows 0-7: q (*LOG2E), 8-15: k, 16-79: v.
// c-loop chunked (16 channels/chunk, outer loop NOT unrolled) to keep live
// x-registers at 16 and interleave loads with FMAs.
// V keys permuted within 32-groups: slot = ((k>>2)&3)*8 + ((k>>4)&1)*4 + (k&3)
// so PV's B-operand slot k'=quad*8+j matches QK's D[key][q] output rows.
// ---------------------------------------------------------------------------
__global__ __launch_bounds__(256)
void proj6(const float* __restrict__ x,
           const float* __restrict__ Wq, const float* __restrict__ bq,
           const float* __restrict__ Wk, const float* __restrict__ bk,
           const float* __restrict__ Wv, const float* __restrict__ bv,
           ushort* __restrict__ qbuf, ushort* __restrict__ kbuf,
           ushort* __restrict__ vfw)
{
    const int tid = threadIdx.x;
    const int px  = tid & 63;
    const int og  = __builtin_amdgcn_readfirstlane(tid >> 6);  // 0..3, wave-uniform
    const int blk = blockIdx.x;
    const int b     = blk / (4 * QTILES);
    const int rem   = blk % (4 * QTILES);
    const int ptile = rem >> 2;
    const int rq    = rem & 3;
    const int p     = ptile * 64 + px;
    const int r0    = rq * 20 + og * 5;          // first of this thread's 5 rows

    const float* wr[5];
#pragma unroll
    for (int r = 0; r < 5; ++r) {
        const int row = r0 + r;
        wr[r] = (row < 8) ? (Wq + row * 64)
              : (row < 16) ? (Wk + (row - 8) * 64)
              : (Wv + (row - 16) * 64);
    }

    const float* xb = x + (size_t)b * 64 * PP + p;
    float acc[5] = {0.f, 0.f, 0.f, 0.f, 0.f};

#pragma unroll 1
    for (int c0 = 0; c0 < 64; c0 += 16) {
        float xv[16];
#pragma unroll
        for (int i = 0; i < 16; ++i)
            xv[i] = xb[(size_t)(c0 + i) * PP];
#pragma unroll
        for (int i = 0; i < 16; ++i) {
#pragma unroll
            for (int r = 0; r < 5; ++r)
                acc[r] = fmaf(wr[r][c0 + i], xv[i], acc[r]);
        }
    }

#pragma unroll
    for (int r = 0; r < 5; ++r) {
        const int row = r0 + r;
        if (row < 8) {
            const float v = (acc[r] + bq[row]) * LOG2E;
            qbuf[((size_t)b * PP + p) * 8 + row] = f2bf(v);
        } else if (row < 16) {
            const float v = acc[r] + bk[row - 8];
            kbuf[((size_t)b * PP + p) * 8 + (row - 8)] = f2bf(v);
        } else {
            const int co = row - 16;
            const float v = acc[r] + bv[co];
            const int pl = p & 31;     // slot permutation within 32-group
            const int ps = (p & ~31) | ((((pl >> 2) & 3) << 3) | (((pl >> 4) & 1) << 2) | (pl & 3));
            vfw[((size_t)b * 64 + co) * PP + ps] = f2bf(v);
        }
    }
}

// ---------------------------------------------------------------------------
// Kernel 2: LDS-staged MFMA flash attention, 3-buffer counted-vmcnt pipeline,
// XCD-partitioned (round-7 verbatim). Grid = QTILES*8 blocks of 128;
// blockIdx = qt*8 + gb, gb = g*BB+b (round-robin XCD assignment -> one (g,b)
// key-slice per XCD; FETCH 10.5MB -> 1.9MB measured).
// Per 9216B buffer: V 8KB (rows XOR-swizzled) + K 1KB; 3 buffers; epilogue
// smerge (16KB) overlays bufs 0-1 after the final vmcnt(0)+barrier.
// Each wave issues EXACTLY 5 gload_lds per stage; vmcnt(5) at iter top
// proves stage(t) landed; barrier fences buf reuse. Final tile peeled.
// QK: E = mfma(A=K, B=Q) -> D[key][q]; P = Schraudolph bf16 bits = PV
// B-operand (V key-permuted); lsum = ones-row MFMA.
// ---------------------------------------------------------------------------
__global__ __launch_bounds__(128, 3)
void attn13(const ushort* __restrict__ qbuf, const ushort* __restrict__ kbuf,
            const ushort* __restrict__ vfw,
            ushort* __restrict__ accp, float* __restrict__ lsump,
            int keysPerG, int numTiles)
{
    // 0..27648: 3x (V 8KB + K 1KB) | 27648..27904: slsum
    // smerge (16KB f32) overlays 0..16384 after the loop.
    __shared__ __align__(16) char sbuf[27904];
    float* smerge = (float*)sbuf;
    float* slsum  = (float*)(sbuf + 27648);

    const int tid  = threadIdx.x;
    const int lane = tid & 63;
    const int kh   = tid >> 6;        // wave id = key half (0/1)
    const int col  = lane & 15;
    const int quad = lane >> 4;

    // XCD-aware decode: consecutive blockIdx round-robin across the 8 XCDs,
    // so gb = blockIdx & 7 pins each (g,b) key-slice to one XCD's L2.
    const int qt = blockIdx.x >> 3;   // 0..143
    const int gb = blockIdx.x & 7;    // 0..7 = g*BB+b
    const int b  = gb % BB;
    const int g  = gb / BB;
    const int q0 = qt * 64;

    const short8 zf = {0, 0, 0, 0, 0, 0, 0, 0};
    const short vone = (short)0x3F80;                 // bf16 1.0
    const short8 vones = {vone, vone, vone, vone, vone, vone, vone, vone};

    // Q fragments (B-operand: B[k=d=quad*8+j][n=q=col]); only quad 0 real.
    short8 qfragB[4];
#pragma unroll
    for (int qh = 0; qh < 4; ++qh)
        qfragB[qh] = (quad == 0)
            ? *(const short8*)(qbuf + ((size_t)b * PP + q0 + qh * 16 + col) * 8)
            : zf;

    floatx4 acc[4][4];
#pragma unroll
    for (int qh = 0; qh < 4; ++qh)
#pragma unroll
        for (int cb = 0; cb < 4; ++cb) acc[qh][cb] = (floatx4){0.f, 0.f, 0.f, 0.f};
    floatx4 accLh[4];
#pragma unroll
    for (int qh = 0; qh < 4; ++qh) accLh[qh] = (floatx4){0.f, 0.f, 0.f, 0.f};

    const ushort* kB = kbuf + (size_t)b * PP * 8;
    const ushort* vB = vfw + (size_t)b * 64 * PP;
    const int kwbase = g * keysPerG;

    // per-lane staging geometry: lane covers (row-in-8-group vr, chunk_pos lane&7)
    const int vr = lane >> 3;                 // 0..7
    const int vc = (lane & 7) ^ vr;           // swizzled logical chunk for this slot

    auto stage = [&](int t) {
        const int kw = kwbase + t * 64;
        char* Vb = sbuf + 9216 * (t % 3);
        // K: 64 rows x 16B; BOTH waves issue it (same bytes) so each wave's
        // per-stage gload count is exactly 5 (vmcnt accounting).
        gload16_lds(kB + (size_t)(kw + lane) * 8, Vb + 8192);
        const int j0 = kh * 4;
#pragma unroll
        for (int j = 0; j < 4; ++j) {
            const int r = (j0 + j) * 8 + vr;                       // ch row 0..63
            gload16_lds(vB + (size_t)r * PP + kw + vc * 8, Vb + (j0 + j) * 1024);
        }
    };

    auto compute = [&](int t) {
        const char* Vb = sbuf + 9216 * (t % 3);
        const ushort* Kl = (const ushort*)(Vb + 8192);
        // K A-operand rows = keys; all quads read quad0's 16B (broadcast, slots
        // >=8 multiply Q zeros).
        const short8 kf0 = *(const short8*)(Kl + (kh * 32 + col) * 8);
        const short8 kf1 = *(const short8*)(Kl + (kh * 32 + 16 + col) * 8);
        short8 vf[4];
        const int ce = (kh * 4 + quad) ^ (col & 7);   // swizzled chunk to read
#pragma unroll
        for (int cb = 0; cb < 4; ++cb)
            vf[cb] = *(const short8*)(Vb + ((cb * 16 + col) * 8 + ce) * 16);

#pragma unroll
        for (int qh = 0; qh < 4; ++qh) {
            const floatx4 E0 = __builtin_amdgcn_mfma_f32_16x16x32_bf16(
                kf0, qfragB[qh], (floatx4){0.f, 0.f, 0.f, 0.f}, 0, 0, 0);
            const floatx4 E1 = __builtin_amdgcn_mfma_f32_16x16x32_bf16(
                kf1, qfragB[qh], (floatx4){0.f, 0.f, 0.f, 0.f}, 0, 0, 0);

            // Schraudolph bf16 P, packed pairs (slots quad*8 + 0..7)
            intx4 pi;
            pi.x = (int)exp2_pk_bf16(E0[0], E0[1]);
            pi.y = (int)exp2_pk_bf16(E0[2], E0[3]);
            pi.z = (int)exp2_pk_bf16(E1[0], E1[1]);
            pi.w = (int)exp2_pk_bf16(E1[2], E1[3]);
            const short8 pf = __builtin_bit_cast(short8, pi);

            // lsum on the matrix pipe: D[r][c] = sum_k P[k][c] for every r.
            accLh[qh] = __builtin_amdgcn_mfma_f32_16x16x32_bf16(vones, pf, accLh[qh], 0, 0, 0);
#pragma unroll
            for (int cb = 0; cb < 4; ++cb)
                acc[qh][cb] = __builtin_amdgcn_mfma_f32_16x16x32_bf16(
                    vf[cb], pf, acc[qh][cb], 0, 0, 0);
        }
    };

    // ---- 3-buffer counted-vmcnt main loop ----
    stage(0);
    stage(1);                                   // outstanding: 10 per wave
    for (int t = 0; t < numTiles - 1; ++t) {
        asm volatile("s_waitcnt vmcnt(5)" ::: "memory");   // stage(t) landed
        __builtin_amdgcn_s_barrier();                      // both waves agree
        __builtin_amdgcn_sched_barrier(0);
        if (t + 2 < numTiles) stage(t + 2);                // buf[(t+2)%3]
        compute(t);
    }
    asm volatile("s_waitcnt vmcnt(0)" ::: "memory");       // last stage landed
    __builtin_amdgcn_s_barrier();
    __builtin_amdgcn_sched_barrier(0);
    compute(numTiles - 1);
    __syncthreads();            // all buf reads done before smerge overlay

    // ---- merge the two waves' key-halves via LDS; wave 0 stores ----
    if (kh == 1) {
#pragma unroll
        for (int qh = 0; qh < 4; ++qh)
#pragma unroll
            for (int cb = 0; cb < 4; ++cb)
#pragma unroll
                for (int r = 0; r < 4; ++r)
                    smerge[(cb * 16 + quad * 4 + r) * 64 + qh * 16 + col] = acc[qh][cb][r];
        if (quad == 0)
#pragma unroll
            for (int qh = 0; qh < 4; ++qh)
                slsum[qh * 16 + col] = accLh[qh][0];
    }
    __syncthreads();
    if (kh == 0) {
        ushort* ab = accp + ((size_t)g * BB + b) * CC * PP;
#pragma unroll
        for (int qh = 0; qh < 4; ++qh)
#pragma unroll
            for (int cb = 0; cb < 4; ++cb)
#pragma unroll
                for (int r = 0; r < 4; ++r) {
                    const int c = cb * 16 + quad * 4 + r;
                    const float v = acc[qh][cb][r] + smerge[c * 64 + qh * 16 + col];
                    ab[(size_t)c * PP + q0 + qh * 16 + col] = f2bf(v);
                }
        if (quad == 0) {
            float* lb = lsump + ((size_t)g * BB + b) * PP + q0;
#pragma unroll
            for (int qh = 0; qh < 4; ++qh)
                lb[qh * 16 + col] = accLh[qh][0] + slsum[qh * 16 + col];
        }
    }
}

// ---------------------------------------------------------------------------
// Kernel 3: combine G partials, normalize, + gamma*attn + x. 576 x 256,
// 8 consecutive pixels per thread (layouts already [b][c][p]-major).
// ---------------------------------------------------------------------------
__global__ __launch_bounds__(256)
void combine(const ushort* __restrict__ accp, const float* __restrict__ lsump,
             const float* __restrict__ x, const float* __restrict__ gamma,
             float* __restrict__ out, int G)
{
    const size_t i8 = ((size_t)blockIdx.x * 256 + threadIdx.x) * 8;
    const int b = (int)(i8 / ((size_t)CC * PP));
    const int p = (int)(i8 % PP);
    const float gm = gamma[0];

    float asum[8] = {}, lst[8] = {};
    for (int g = 0; g < G; ++g) {
        const uint4 av = *(const uint4*)(accp + (size_t)g * (BB * CC * PP) + i8);
        const unsigned int u[4] = {av.x, av.y, av.z, av.w};
#pragma unroll
        for (int k = 0; k < 4; ++k) {
            asum[2 * k]     += __uint_as_float(u[k] << 16);
            asum[2 * k + 1] += __uint_as_float(u[k] & 0xffff0000u);
        }
        const float* lp = lsump + ((size_t)g * BB + b) * PP + p;
        const float4 l0 = *(const float4*)lp;
        const float4 l1 = *(const float4*)(lp + 4);
        lst[0] += l0.x; lst[1] += l0.y; lst[2] += l0.z; lst[3] += l0.w;
        lst[4] += l1.x; lst[5] += l1.y; lst[6] += l1.z; lst[7] += l1.w;
    }

    const float4 x0 = *(const float4*)(x + i8);
    const float4 x1 = *(const float4*)(x + i8 + 4);
    float o[8] = {x0.x, x0.y, x0.z, x0.w, x1.x, x1.y, x1.z, x1.w};
#pragma unroll
    for (int j = 0; j < 8; ++j)
        o[j] = fmaf(asum[j], gm / fmaxf(lst[j], 1e-30f), o[j]);
    *(float4*)(out + i8)     = make_float4(o[0], o[1], o[2], o[3]);
    *(float4*)(out + i8 + 4) = make_float4(o[4], o[5], o[6], o[7]);
}

// ---------------------------------------------------------------------------
extern "C" void kernel_launch(void* const* d_in, const int* in_sizes, int n_in,
                              void* d_out, int out_size, void* d_ws, size_t ws_size,
                              hipStream_t stream)
{
    const float* x     = (const float*)d_in[0];
    const float* Wq    = (const float*)d_in[1];
    const float* bq    = (const float*)d_in[2];
    const float* Wk    = (const float*)d_in[3];
    const float* bk    = (const float*)d_in[4];
    const float* Wv    = (const float*)d_in[5];
    const float* bv    = (const float*)d_in[6];
    const float* gamma = (const float*)d_in[7];
    float* out = (float*)d_out;

    // ws: qbuf | kbuf | vfw (bf16) | accp (bf16, G slots) | lsump (f32)
    const size_t nQK  = (size_t)BB * PP * 8;        // elems
    const size_t nV   = (size_t)BB * CC * PP;
    // G=4 fixed: g*BB+b spans exactly 8 values = 8 XCDs (attn13 swizzle).
    const int G = 4;
    const int keysPerG = PP / G;
    const int numTiles = keysPerG / 64;             // 36

    ushort* qbuf = (ushort*)d_ws;
    ushort* kbuf = qbuf + nQK;
    ushort* vfw  = kbuf + nQK;
    ushort* accp = vfw + nV;
    float* lsump = (float*)(accp + (size_t)G * nV);
    (void)ws_size;

    proj6<<<dim3(BB * 4 * QTILES), dim3(256), 0, stream>>>(
        x, Wq, bq, Wk, bk, Wv, bv, qbuf, kbuf, vfw);
    attn13<<<dim3(QTILES * 8), dim3(128), 0, stream>>>(
        qbuf, kbuf, vfw, accp, lsump, keysPerG, numTiles);
    combine<<<dim3(576), dim3(256), 0, stream>>>(
        accp, lsump, x, gamma, out, G);
}